// Round 14
// baseline (433.500 us; speedup 1.0000x reference)
//
#include <hip/hip_runtime.h>
#include <hip/hip_fp16.h>
#include <math.h>

// Problem constants (match reference)
constexpr int N_NODES = 65536;
constexpr int N_EDGES = 2097152;
constexpr int F_IN    = 128;
constexpr int H_DIM   = 256;
constexpr int O_DIM   = 128;
constexpr int N_GRAPH = 256;
constexpr int V_SIZE  = 1000;

// 256 buckets of 256 nodes (bucket = col>>8); 256 edge-blocks of 8192 edges.
constexpr int EPB  = 8192;
constexpr int NBLK = N_EDGES / EPB;   // 256
constexpr int BCAP = 9216;            // k_build LDS record capacity
constexpr float FXP = 16777216.0f;    // 2^24

// ---------------- init: pool=0; block 0 does graph counts (sorted batch) ----

__global__ void k_init(float* __restrict__ pool, const int* __restrict__ batch,
                       float* __restrict__ cntf) {
    int i = blockIdx.x * blockDim.x + threadIdx.x;
    pool[i] = 0.0f;                    // grid covers exactly N_GRAPH*O_DIM
    if (blockIdx.x == 0) {
        int g = threadIdx.x;
        int lo = 0, hi = N_NODES;
        while (lo < hi) { int m = (lo + hi) >> 1; if (batch[m] < g) lo = m + 1; else hi = m; }
        int start = lo;
        lo = 0; hi = N_NODES;
        while (lo < hi) { int m = (lo + hi) >> 1; if (batch[m] <= g) lo = m + 1; else hi = m; }
        cntf[g] = (float)(lo - start);
    }
}

// ---------------- cfW1 = cf @ W1 -> fp16 table [1000 x 256] (512 KB) --------

__global__ void k_cfw1(const float* __restrict__ cf, const float* __restrict__ W1,
                       __half* __restrict__ cfW1) {
    __shared__ float xs[8 * F_IN];    // 4 KB
    int rb = blockIdx.x * 8;          // 125 blocks x 8 rows = 1000
    int t  = threadIdx.x;
    #pragma unroll
    for (int p = 0; p < 4; ++p) {
        int idx = p * 256 + t;
        int r = idx >> 7, k = idx & 127;
        xs[idx] = cf[(size_t)(rb + r) * F_IN + k];
    }
    __syncthreads();
    float acc[8] = {};
    for (int k = 0; k < F_IN; ++k) {
        float w = W1[k * H_DIM + t];
        #pragma unroll
        for (int j = 0; j < 8; ++j) acc[j] += xs[j * F_IN + k] * w;
    }
    #pragma unroll
    for (int j = 0; j < 8; ++j)
        cfW1[(size_t)(rb + j) * H_DIM + t] = __float2half(acc[j]);
}

// ---------------- stage A: per-block bucket histogram (LDS) ----------------

__global__ void k_hist(const int* __restrict__ col, int* __restrict__ hist) {
    __shared__ int h[256];
    int t = threadIdx.x;
    h[t] = 0;
    __syncthreads();
    int base = blockIdx.x * EPB;
    #pragma unroll
    for (int i = 0; i < EPB / 256; ++i)
        atomicAdd(&h[col[base + i * 256 + t] >> 8], 1);
    __syncthreads();
    hist[t * NBLK + blockIdx.x] = h[t];   // bucket-major for the scan
}

// ---------------- scan (partial per-256-chunk + block sums) ----------------

__global__ void k_scan1(const int* __restrict__ in, int* __restrict__ out,
                        int* __restrict__ bsum) {
    __shared__ int s[256];
    int tid = threadIdx.x;
    int i = blockIdx.x * 256 + tid;
    int v = in[i];
    s[tid] = v;
    __syncthreads();
    for (int d = 1; d < 256; d <<= 1) {
        int t = (tid >= d) ? s[tid - d] : 0;
        __syncthreads();
        s[tid] += t;
        __syncthreads();
    }
    out[i] = s[tid] - v;
    if (tid == 255) bsum[blockIdx.x] = s[255];
}

__global__ void k_scan2(int* __restrict__ bsum) {
    __shared__ int s[256];
    int tid = threadIdx.x;
    int v = bsum[tid];
    s[tid] = v;
    __syncthreads();
    for (int d = 1; d < 256; d <<= 1) {
        int t = (tid >= d) ? s[tid - d] : 0;
        __syncthreads();
        s[tid] += t;
        __syncthreads();
    }
    bsum[tid] = s[tid] - v;
}

// ---------------- stage C: partition into int2 records ----------------------
// rec.x = src:16 | dst8:8 | vocab_hi:8 ; rec.y = vocab_lo:2<<16 | ew_fp16:16

__global__ void k_part(const int* __restrict__ row, const int* __restrict__ col,
                       const float* __restrict__ ew, const int* __restrict__ nidx,
                       const int* __restrict__ hoffs, const int* __restrict__ bsum,
                       int2* __restrict__ part) {
    __shared__ int cur[256];
    int t = threadIdx.x;
    cur[t] = hoffs[t * NBLK + blockIdx.x] + bsum[t];
    __syncthreads();
    int base = blockIdx.x * EPB;
    for (int i = 0; i < EPB / 256; ++i) {
        int e = base + i * 256 + t;
        int r = row[e], c = col[e];
        unsigned hw = (unsigned)__half_as_ushort(__float2half(ew[e]));
        int vb = nidx[r];
        int slot = atomicAdd(&cur[c >> 8], 1);
        int2 rec;
        rec.x = (r << 16) | ((c & 255) << 8) | (vb >> 2);
        rec.y = (int)(((unsigned)(vb & 3) << 16) | hw);
        part[slot] = rec;
    }
}

// ---------------- stage D: per-bucket deg/dis + offs + final CSR ------------
// single pass over part (LDS record cache); csr.y = raw ew, k_nrm pre-scales.

__global__ void k_build(const int* __restrict__ hoffs, const int* __restrict__ bsum,
                        const int2* __restrict__ part, int2* __restrict__ csr,
                        float* __restrict__ dis, int* __restrict__ offs) {
    __shared__ int2 recs[BCAP];                  // 72 KB
    __shared__ unsigned long long dc[256];       // 2 KB
    __shared__ int sc[256];
    __shared__ int cur[256];
    int t = threadIdx.x;
    int bucket = blockIdx.x;
    dc[t] = 0ULL;
    __syncthreads();
    int start = hoffs[bucket * NBLK] + bsum[bucket];
    int end   = (bucket == 255) ? N_EDGES : (hoffs[(bucket + 1) * NBLK] + bsum[bucket + 1]);
    int n = end - start;
    for (int j = t; j < n; j += 256) {
        int2 rec = part[start + j];
        if (j < BCAP) recs[j] = rec;
        int dst = (rec.x >> 8) & 255;
        float w = __half2float(__ushort_as_half((unsigned short)(rec.y & 0xFFFF)));
        atomicAdd(&dc[dst], (1ULL << 40) |
                  (unsigned long long)(unsigned)(w * FXP + 0.5f));
    }
    __syncthreads();
    unsigned long long v = dc[t];
    float deg = 1.0f + (float)(v & 0xFFFFFFFFFFULL) * (1.0f / FXP);   // self-loop +1
    dis[bucket * 256 + t] = 1.0f / sqrtf(deg);                        // deg >= 1
    int cnt = (int)(v >> 40);
    sc[t] = cnt;
    __syncthreads();
    for (int d = 1; d < 256; d <<= 1) {
        int x = (t >= d) ? sc[t - d] : 0;
        __syncthreads();
        sc[t] += x;
        __syncthreads();
    }
    int node_off = start + sc[t] - cnt;
    offs[bucket * 256 + t] = node_off;
    cur[t] = node_off;
    if (bucket == 255 && t == 255) offs[N_NODES] = N_EDGES;
    __syncthreads();
    for (int j = t; j < n; j += 256) {
        int2 rec = (j < BCAP) ? recs[j] : part[start + j];
        int dst = (rec.x >> 8) & 255;
        unsigned src = ((unsigned)rec.x) >> 16;
        int vb = ((rec.x & 255) << 2) | ((rec.y >> 16) & 3);
        float w = __half2float(__ushort_as_half((unsigned short)(rec.y & 0xFFFF)));
        int slot = atomicAdd(&cur[dst], 1);
        int2 e;
        e.x = (int)((src << 10) | (unsigned)vb);
        e.y = __float_as_int(w);
        csr[slot] = e;
    }
}

// ---------------- nrm: csr.y = dis[src] * ew  (dis[dst] applied in agg) -----

__global__ void k_nrm(int2* __restrict__ csr, const float* __restrict__ dis) {
    int i = blockIdx.x * blockDim.x + threadIdx.x;
    int2 e = csr[i];
    e.y = __float_as_int(dis[e.x >> 10] * __int_as_float(e.y));
    csr[i] = e;
}

// ---------------- layer-1: gather-aggregate cfW1 rows -> h1 (fp16) ----------
// wave per node; lane handles 4 halves (int2); unroll 8 (4 KB in flight/wave).

__global__ void k_agg1(const int2* __restrict__ cfW1, const int* __restrict__ nidx,
                       const float* __restrict__ dis, const int* __restrict__ offs,
                       const int2* __restrict__ csr, const float4* __restrict__ b1f4,
                       int2* __restrict__ h1) {
    int wave = threadIdx.x >> 6;
    int lane = threadIdx.x & 63;
    int c = blockIdx.x * 4 + wave;
    float d = dis[c];
    int2 sp = cfW1[(size_t)nidx[c] * 64 + lane];
    float2 sa = __half22float2(*(__half2*)&sp.x);
    float2 sb = __half22float2(*(__half2*)&sp.y);
    float4 esum = {0.f, 0.f, 0.f, 0.f};
    int a0 = offs[c], a1 = offs[c + 1];
    int s = a0;
    for (; s + 8 <= a1; s += 8) {
        int2 e[8];
        #pragma unroll
        for (int u = 0; u < 8; ++u) e[u] = csr[s + u];
        int2 v[8];
        #pragma unroll
        for (int u = 0; u < 8; ++u)
            v[u] = cfW1[(size_t)(e[u].x & 1023) * 64 + lane];
        #pragma unroll
        for (int u = 0; u < 8; ++u) {
            float n = __int_as_float(e[u].y);
            float2 va = __half22float2(*(__half2*)&v[u].x);
            float2 vb = __half22float2(*(__half2*)&v[u].y);
            esum.x += va.x * n; esum.y += va.y * n;
            esum.z += vb.x * n; esum.w += vb.y * n;
        }
    }
    for (; s < a1; ++s) {
        int2 e0 = csr[s];
        int2 v0 = cfW1[(size_t)(e0.x & 1023) * 64 + lane];
        float n = __int_as_float(e0.y);
        float2 va = __half22float2(*(__half2*)&v0.x);
        float2 vb = __half22float2(*(__half2*)&v0.y);
        esum.x += va.x * n; esum.y += va.y * n;
        esum.z += vb.x * n; esum.w += vb.y * n;
    }
    float4 bb = b1f4[lane];
    float dd = d * d;
    float r0 = bb.x + sa.x * dd + d * esum.x;
    float r1 = bb.y + sa.y * dd + d * esum.y;
    float r2 = bb.z + sb.x * dd + d * esum.z;
    float r3 = bb.w + sb.y * dd + d * esum.w;
    r0 = r0 > 0.f ? r0 : 0.f;  r1 = r1 > 0.f ? r1 : 0.f;
    r2 = r2 > 0.f ? r2 : 0.f;  r3 = r3 > 0.f ? r3 : 0.f;
    float2 p0 = {r0, r1}, p1 = {r2, r3};
    __half2 ha = __float22half2_rn(p0);
    __half2 hb = __float22half2_rn(p1);
    int2 outv;
    outv.x = *(int*)&ha;
    outv.y = *(int*)&hb;
    h1[(size_t)c * 64 + lane] = outv;
}

// ---------------- GEMM2: h1 (fp16) [N,256] @ W2 -> xw2 (fp16) [N,128] --------

__global__ void k_gemm2(const __half* __restrict__ h1, const float* __restrict__ W2,
                        __half* __restrict__ xw2h) {
    __shared__ float xs[32 * H_DIM];  // 32 KB
    int nb = blockIdx.x * 32;
    int t  = threadIdx.x;
    const int4* src = (const int4*)(h1 + (size_t)nb * H_DIM);
    float4* dst4 = (float4*)xs;
    #pragma unroll
    for (int p = 0; p < 4; ++p) {
        int4 pk = src[p * 256 + t];
        __half2 ha = *(__half2*)&pk.x, hb = *(__half2*)&pk.y;
        __half2 hc = *(__half2*)&pk.z, hd = *(__half2*)&pk.w;
        float2 fa = __half22float2(ha), fb = __half22float2(hb);
        float2 fc = __half22float2(hc), fd = __half22float2(hd);
        float4 A; A.x = fa.x; A.y = fa.y; A.z = fb.x; A.w = fb.y;
        float4 B; B.x = fc.x; B.y = fc.y; B.z = fd.x; B.w = fd.y;
        dst4[(p * 256 + t) * 2]     = A;
        dst4[(p * 256 + t) * 2 + 1] = B;
    }
    __syncthreads();
    int o  = t & 63;
    int jg = t >> 6;
    const float* xsj = xs + jg * 8 * H_DIM;
    float acc[8][2] = {};
    for (int k = 0; k < H_DIM; ++k) {
        float w0 = W2[k * O_DIM + o];
        float w1 = W2[k * O_DIM + o + 64];
        #pragma unroll
        for (int j = 0; j < 8; ++j) {
            float x = xsj[j * H_DIM + k];
            acc[j][0] += x * w0; acc[j][1] += x * w1;
        }
    }
    #pragma unroll
    for (int j = 0; j < 8; ++j) {
        size_t base = (size_t)(nb + jg * 8 + j) * O_DIM + o;
        xw2h[base]      = __float2half(acc[j][0]);
        xw2h[base + 64] = __float2half(acc[j][1]);
    }
}

// ---------------- layer-2 agg + relu + LDS-reduced pool (4 nodes/block) ------

__global__ void k_agg2_pool(const __half2* __restrict__ xw2h, const float* __restrict__ b2,
                            const float* __restrict__ dis, const int* __restrict__ offs,
                            const int2* __restrict__ csr, const int* __restrict__ batch,
                            float* __restrict__ pool) {
    __shared__ float2 red[4][64];
    __shared__ int bgs[4];
    int wave = threadIdx.x >> 6;
    int lane = threadIdx.x & 63;
    int c = blockIdx.x * 4 + wave;
    float d = dis[c];
    float2 self = __half22float2(xw2h[(size_t)c * 64 + lane]);
    float2 bb = ((const float2*)b2)[lane];
    float2 esum = {0.f, 0.f};
    int s0 = offs[c], s1 = offs[c + 1];
    int s = s0;
    for (; s + 8 <= s1; s += 8) {
        int2 e[8];
        #pragma unroll
        for (int u = 0; u < 8; ++u) e[u] = csr[s + u];
        float2 v[8];
        #pragma unroll
        for (int u = 0; u < 8; ++u)
            v[u] = __half22float2(xw2h[(size_t)(e[u].x >> 10) * 64 + lane]);
        #pragma unroll
        for (int u = 0; u < 8; ++u) {
            float n = __int_as_float(e[u].y);
            esum.x += v[u].x * n; esum.y += v[u].y * n;
        }
    }
    for (; s < s1; ++s) {
        int2 e0 = csr[s];
        float2 v0 = __half22float2(xw2h[(size_t)(e0.x >> 10) * 64 + lane]);
        float n0 = __int_as_float(e0.y);
        esum.x += v0.x * n0; esum.y += v0.y * n0;
    }
    float dd = d * d;
    float2 acc;
    acc.x = bb.x + self.x * dd + d * esum.x;
    acc.y = bb.y + self.y * dd + d * esum.y;
    acc.x = acc.x > 0.0f ? acc.x : 0.0f;
    acc.y = acc.y > 0.0f ? acc.y : 0.0f;
    red[wave][lane] = acc;
    if (lane == 0) bgs[wave] = batch[c];
    __syncthreads();
    if (wave == 0) {
        float2 a = red[0][lane];
        int cg = bgs[0];
        #pragma unroll
        for (int w = 1; w < 4; ++w) {
            int g = bgs[w];
            float2 r = red[w][lane];
            if (g == cg) { a.x += r.x; a.y += r.y; }
            else {
                atomicAdd(&pool[cg * O_DIM + 2 * lane], a.x);
                atomicAdd(&pool[cg * O_DIM + 2 * lane + 1], a.y);
                a = r; cg = g;
            }
        }
        atomicAdd(&pool[cg * O_DIM + 2 * lane], a.x);
        atomicAdd(&pool[cg * O_DIM + 2 * lane + 1], a.y);
    }
}

__global__ void k_final(const float* __restrict__ pool, const float* __restrict__ cnt,
                        float* __restrict__ out) {
    int t = blockIdx.x * blockDim.x + threadIdx.x;
    if (t < N_GRAPH * O_DIM) {
        int g = t / O_DIM;
        out[t] = pool[t] / fmaxf(cnt[g], 1.0f);
    }
}

// ---------------- launch ----------------

extern "C" void kernel_launch(void* const* d_in, const int* in_sizes, int n_in,
                              void* d_out, int out_size, void* d_ws, size_t ws_size,
                              hipStream_t stream) {
    const float* cf   = (const float*)d_in[0];   // [V,128]
    const float* W1   = (const float*)d_in[1];   // [128,256]
    const float* b1   = (const float*)d_in[2];   // [256]
    const float* W2   = (const float*)d_in[3];   // [256,128]
    const float* b2   = (const float*)d_in[4];   // [128]
    const float* ew   = (const float*)d_in[5];   // [E]
    const int*   nidx = (const int*)d_in[6];     // [N]
    const int*   eidx = (const int*)d_in[7];     // [2,E]
    const int*   bidx = (const int*)d_in[8];     // [N]
    float* out = (float*)d_out;

    const int* row = eidx;            // source
    const int* col = eidx + N_EDGES;  // target

    // workspace layout (bytes)
    char* ws = (char*)d_ws;
    size_t off = 0;
    int*   hist  = (int*)  (ws + off); off += (size_t)N_NODES * 4;          // 256K
    int*   hoffs = (int*)  (ws + off); off += (size_t)N_NODES * 4;          // 256K
    int*   bsum  = (int*)  (ws + off); off += 4096;
    float* dis   = (float*)(ws + off); off += (size_t)N_NODES * 4;          // 256K
    int*   offs  = (int*)  (ws + off); off += (size_t)(N_NODES + 16) * 4;   // 256K
    int2*  csr   = (int2*) (ws + off); off += (size_t)N_EDGES * 8;          // 16M
    float* pool  = (float*)(ws + off); off += (size_t)(N_GRAPH * O_DIM + N_GRAPH) * 4;
    __half* cfW1 = (__half*)(ws + off); off += (size_t)V_SIZE * H_DIM * 2;  // 512K
    off = (off + 255) & ~(size_t)255;
    int2*  part  = (int2*) (ws + off); off += (size_t)N_EDGES * 8;          // 16M
    __half* h1   = (__half*)(ws + off);                                     // 32M
    __half* xw2h = (__half*)part;    // part dead after k_build
    float* cntf  = pool + N_GRAPH * O_DIM;

    // 1. init (pool zero + graph counts) + cfW1 table + histogram + scan
    k_init<<<N_GRAPH * O_DIM / 256, 256, 0, stream>>>(pool, bidx, cntf);
    k_cfw1<<<V_SIZE / 8, 256, 0, stream>>>(cf, W1, cfW1);
    k_hist<<<NBLK, 256, 0, stream>>>(col, hist);
    k_scan1<<<256, 256, 0, stream>>>(hist, hoffs, bsum);
    k_scan2<<<1, 256, 0, stream>>>(bsum);

    // 2. partition -> per-bucket build -> nrm pre-scale
    k_part<<<NBLK, 256, 0, stream>>>(row, col, ew, nidx, hoffs, bsum, part);
    k_build<<<256, 256, 0, stream>>>(hoffs, bsum, part, csr, dis, offs);
    k_nrm<<<N_EDGES / 256, 256, 0, stream>>>(csr, dis);

    // 3. layer 1: gather-aggregate from the 512 KB cfW1 table (unroll 8) -> h1
    k_agg1<<<N_NODES / 4, 256, 0, stream>>>((const int2*)cfW1, nidx, dis, offs, csr,
                                            (const float4*)b1, (int2*)h1);

    // 4. layer 2: GEMM (fp16 in/out), aggregate + relu + LDS-reduced pool
    k_gemm2<<<N_NODES / 32, 256, 0, stream>>>(h1, W2, xw2h);
    k_agg2_pool<<<N_NODES / 4, 256, 0, stream>>>((const __half2*)xw2h, b2, dis, offs, csr,
                                                 bidx, pool);

    // 5. final divide
    k_final<<<(N_GRAPH * O_DIM + 255) / 256, 256, 0, stream>>>(pool, cntf, out);
}

// Round 15
// 366.778 us; speedup vs baseline: 1.1819x; 1.1819x over previous
//
#include <hip/hip_runtime.h>
#include <hip/hip_fp16.h>
#include <math.h>

// Problem constants (match reference)
constexpr int N_NODES = 65536;
constexpr int N_EDGES = 2097152;
constexpr int F_IN    = 128;
constexpr int H_DIM   = 256;
constexpr int O_DIM   = 128;
constexpr int N_GRAPH = 256;
constexpr int V_SIZE  = 1000;

// 256 buckets of 256 nodes (bucket = col>>8); 256 edge-blocks of 8192 edges.
constexpr int EPB  = 8192;
constexpr int NBLK = N_EDGES / EPB;   // 256
constexpr float FXP = 16777216.0f;    // 2^24

// ---------------- init: pool=0, graph counts (block 0), cfW1 table ----------
// cfW1 = cf @ W1 as fp16 [1000 x 256] (512 KB, stays L2-resident for k_agg1).

__global__ void k_init(float* __restrict__ pool, const int* __restrict__ batch,
                       float* __restrict__ cntf, const float* __restrict__ cf,
                       const float* __restrict__ W1, __half* __restrict__ cfW1) {
    __shared__ float xs[8 * F_IN];    // 4 KB
    int i = blockIdx.x * blockDim.x + threadIdx.x;
    if (i < N_GRAPH * O_DIM) pool[i] = 0.0f;
    if (blockIdx.x == 0) {
        // batch_index sorted: per-graph counts via binary search, no atomics
        int g = threadIdx.x;
        int lo = 0, hi = N_NODES;
        while (lo < hi) { int m = (lo + hi) >> 1; if (batch[m] < g) lo = m + 1; else hi = m; }
        int start = lo;
        lo = 0; hi = N_NODES;
        while (lo < hi) { int m = (lo + hi) >> 1; if (batch[m] <= g) lo = m + 1; else hi = m; }
        cntf[g] = (float)(lo - start);
    }
    if (blockIdx.x < V_SIZE / 8) {    // 125 blocks compute the cfW1 table
        int rb = blockIdx.x * 8;
        int t  = threadIdx.x;
        #pragma unroll
        for (int p = 0; p < 4; ++p) {
            int idx = p * 256 + t;
            int r = idx >> 7, k = idx & 127;
            xs[idx] = cf[(size_t)(rb + r) * F_IN + k];
        }
        __syncthreads();
        float acc[8] = {};
        for (int k = 0; k < F_IN; ++k) {
            float w = W1[k * H_DIM + t];
            #pragma unroll
            for (int j = 0; j < 8; ++j) acc[j] += xs[j * F_IN + k] * w;
        }
        #pragma unroll
        for (int j = 0; j < 8; ++j)
            cfW1[(size_t)(rb + j) * H_DIM + t] = __float2half(acc[j]);
    }
}

// ---------------- stage A: per-block bucket histogram (LDS) ----------------

__global__ void k_hist(const int* __restrict__ col, int* __restrict__ hist) {
    __shared__ int h[256];
    int t = threadIdx.x;
    h[t] = 0;
    __syncthreads();
    int base = blockIdx.x * EPB;
    #pragma unroll
    for (int i = 0; i < EPB / 256; ++i)
        atomicAdd(&h[col[base + i * 256 + t] >> 8], 1);
    __syncthreads();
    hist[t * NBLK + blockIdx.x] = h[t];   // bucket-major for the scan
}

// ---------------- scan (partial per-256-chunk + block sums) ----------------

__global__ void k_scan1(const int* __restrict__ in, int* __restrict__ out,
                        int* __restrict__ bsum) {
    __shared__ int s[256];
    int tid = threadIdx.x;
    int i = blockIdx.x * 256 + tid;
    int v = in[i];
    s[tid] = v;
    __syncthreads();
    for (int d = 1; d < 256; d <<= 1) {
        int t = (tid >= d) ? s[tid - d] : 0;
        __syncthreads();
        s[tid] += t;
        __syncthreads();
    }
    out[i] = s[tid] - v;
    if (tid == 255) bsum[blockIdx.x] = s[255];
}

__global__ void k_scan2(int* __restrict__ bsum) {
    __shared__ int s[256];
    int tid = threadIdx.x;
    int v = bsum[tid];
    s[tid] = v;
    __syncthreads();
    for (int d = 1; d < 256; d <<= 1) {
        int t = (tid >= d) ? s[tid - d] : 0;
        __syncthreads();
        s[tid] += t;
        __syncthreads();
    }
    bsum[tid] = s[tid] - v;
}

// ---------------- stage C: partition into int2 records ----------------------
// rec.x = src:16 | dst8:8 | vocab_hi:8 ; rec.y = vocab_lo:2<<16 | ew_fp16:16

__global__ void k_part(const int* __restrict__ row, const int* __restrict__ col,
                       const float* __restrict__ ew, const int* __restrict__ nidx,
                       const int* __restrict__ hoffs, const int* __restrict__ bsum,
                       int2* __restrict__ part) {
    __shared__ int cur[256];
    int t = threadIdx.x;
    cur[t] = hoffs[t * NBLK + blockIdx.x] + bsum[t];
    __syncthreads();
    int base = blockIdx.x * EPB;
    for (int i = 0; i < EPB / 256; ++i) {
        int e = base + i * 256 + t;
        int r = row[e], c = col[e];
        unsigned hw = (unsigned)__half_as_ushort(__float2half(ew[e]));
        int vb = nidx[r];
        int slot = atomicAdd(&cur[c >> 8], 1);
        int2 rec;
        rec.x = (r << 16) | ((c & 255) << 8) | (vb >> 2);
        rec.y = (int)(((unsigned)(vb & 3) << 16) | hw);
        part[slot] = rec;
    }
}

// ---------------- stage D1: per-bucket deg/dis + offs (pass 1) --------------

__global__ void k_build1(const int* __restrict__ hoffs, const int* __restrict__ bsum,
                         const int2* __restrict__ part, float* __restrict__ dis,
                         int* __restrict__ offs) {
    __shared__ unsigned long long dc[256];
    __shared__ int sc[256];
    int t = threadIdx.x;
    int bucket = blockIdx.x;
    dc[t] = 0ULL;
    __syncthreads();
    int start = hoffs[bucket * NBLK] + bsum[bucket];
    int end   = (bucket == 255) ? N_EDGES : (hoffs[(bucket + 1) * NBLK] + bsum[bucket + 1]);
    for (int j = start + t; j < end; j += 256) {
        int2 rec = part[j];
        int dst = (rec.x >> 8) & 255;
        float w = __half2float(__ushort_as_half((unsigned short)(rec.y & 0xFFFF)));
        atomicAdd(&dc[dst], (1ULL << 40) |
                  (unsigned long long)(unsigned)(w * FXP + 0.5f));
    }
    __syncthreads();
    unsigned long long v = dc[t];
    float deg = 1.0f + (float)(v & 0xFFFFFFFFFFULL) * (1.0f / FXP);   // self-loop +1
    dis[bucket * 256 + t] = 1.0f / sqrtf(deg);                        // deg >= 1
    int cnt = (int)(v >> 40);
    sc[t] = cnt;
    __syncthreads();
    for (int d = 1; d < 256; d <<= 1) {
        int x = (t >= d) ? sc[t - d] : 0;
        __syncthreads();
        sc[t] += x;
        __syncthreads();
    }
    offs[bucket * 256 + t] = start + sc[t] - cnt;
    if (bucket == 255 && t == 255) offs[N_NODES] = N_EDGES;
}

// ---------------- stage D2: scatter to final CSR with nrm applied -----------
// csr.x = src<<10 | vocab ; csr.y = dis[src] * ew (dis[dst] applied in agg).

__global__ void k_build2(const int* __restrict__ hoffs, const int* __restrict__ bsum,
                         const int2* __restrict__ part, const float* __restrict__ dis,
                         const int* __restrict__ offs, int2* __restrict__ csr) {
    __shared__ int cur[256];
    int t = threadIdx.x;
    int bucket = blockIdx.x;
    cur[t] = offs[bucket * 256 + t];
    __syncthreads();
    int start = hoffs[bucket * NBLK] + bsum[bucket];
    int end   = (bucket == 255) ? N_EDGES : (hoffs[(bucket + 1) * NBLK] + bsum[bucket + 1]);
    for (int j = start + t; j < end; j += 256) {
        int2 rec = part[j];
        int dst = (rec.x >> 8) & 255;
        unsigned src = ((unsigned)rec.x) >> 16;
        int vb = ((rec.x & 255) << 2) | ((rec.y >> 16) & 3);
        float w = __half2float(__ushort_as_half((unsigned short)(rec.y & 0xFFFF)));
        float nm = dis[src] * w;
        int slot = atomicAdd(&cur[dst], 1);
        int2 e;
        e.x = (int)((src << 10) | (unsigned)vb);
        e.y = __float_as_int(nm);
        csr[slot] = e;
    }
}

// ---------------- layer-1: gather-aggregate cfW1 rows -> h1 (fp16) ----------
// wave per node; lane = 4 halves (int2). csr loads via wave-uniform (scalar)
// index to steer them onto the s_load path (frees vector line budget).

__global__ void k_agg1(const int2* __restrict__ cfW1, const int* __restrict__ nidx,
                       const float* __restrict__ dis, const int* __restrict__ offs,
                       const int2* __restrict__ csr, const float4* __restrict__ b1f4,
                       int2* __restrict__ h1) {
    int wave = threadIdx.x >> 6;
    int lane = threadIdx.x & 63;
    int c = blockIdx.x * 4 + wave;
    float d = dis[c];
    int2 sp = cfW1[(size_t)nidx[c] * 64 + lane];
    float2 sa = __half22float2(*(__half2*)&sp.x);
    float2 sb = __half22float2(*(__half2*)&sp.y);
    float4 esum = {0.f, 0.f, 0.f, 0.f};
    int a0 = offs[c], a1 = offs[c + 1];
    int s = a0;
    for (; s + 8 <= a1; s += 8) {
        int sb_i = __builtin_amdgcn_readfirstlane(s);
        int2 e[8];
        #pragma unroll
        for (int u = 0; u < 8; ++u) e[u] = csr[sb_i + u];
        int2 v[8];
        #pragma unroll
        for (int u = 0; u < 8; ++u)
            v[u] = cfW1[(size_t)(e[u].x & 1023) * 64 + lane];
        #pragma unroll
        for (int u = 0; u < 8; ++u) {
            float n = __int_as_float(e[u].y);
            float2 va = __half22float2(*(__half2*)&v[u].x);
            float2 vb = __half22float2(*(__half2*)&v[u].y);
            esum.x += va.x * n; esum.y += va.y * n;
            esum.z += vb.x * n; esum.w += vb.y * n;
        }
    }
    for (; s < a1; ++s) {
        int sb_i = __builtin_amdgcn_readfirstlane(s);
        int2 e0 = csr[sb_i];
        int2 v0 = cfW1[(size_t)(e0.x & 1023) * 64 + lane];
        float n = __int_as_float(e0.y);
        float2 va = __half22float2(*(__half2*)&v0.x);
        float2 vb = __half22float2(*(__half2*)&v0.y);
        esum.x += va.x * n; esum.y += va.y * n;
        esum.z += vb.x * n; esum.w += vb.y * n;
    }
    float4 bb = b1f4[lane];
    float dd = d * d;
    float r0 = bb.x + sa.x * dd + d * esum.x;
    float r1 = bb.y + sa.y * dd + d * esum.y;
    float r2 = bb.z + sb.x * dd + d * esum.z;
    float r3 = bb.w + sb.y * dd + d * esum.w;
    r0 = r0 > 0.f ? r0 : 0.f;  r1 = r1 > 0.f ? r1 : 0.f;
    r2 = r2 > 0.f ? r2 : 0.f;  r3 = r3 > 0.f ? r3 : 0.f;
    float2 p0 = {r0, r1}, p1 = {r2, r3};
    __half2 ha = __float22half2_rn(p0);
    __half2 hb = __float22half2_rn(p1);
    int2 outv;
    outv.x = *(int*)&ha;
    outv.y = *(int*)&hb;
    h1[(size_t)c * 64 + lane] = outv;
}

// ---------------- GEMM2: h1 (fp16) [N,256] @ W2 -> xw2 (fp16) [N,128] --------

__global__ void k_gemm2(const __half* __restrict__ h1, const float* __restrict__ W2,
                        __half* __restrict__ xw2h) {
    __shared__ float xs[32 * H_DIM];  // 32 KB
    int nb = blockIdx.x * 32;
    int t  = threadIdx.x;
    const int4* src = (const int4*)(h1 + (size_t)nb * H_DIM);
    float4* dst4 = (float4*)xs;
    #pragma unroll
    for (int p = 0; p < 4; ++p) {
        int4 pk = src[p * 256 + t];
        __half2 ha = *(__half2*)&pk.x, hb = *(__half2*)&pk.y;
        __half2 hc = *(__half2*)&pk.z, hd = *(__half2*)&pk.w;
        float2 fa = __half22float2(ha), fb = __half22float2(hb);
        float2 fc = __half22float2(hc), fd = __half22float2(hd);
        float4 A; A.x = fa.x; A.y = fa.y; A.z = fb.x; A.w = fb.y;
        float4 B; B.x = fc.x; B.y = fc.y; B.z = fd.x; B.w = fd.y;
        dst4[(p * 256 + t) * 2]     = A;
        dst4[(p * 256 + t) * 2 + 1] = B;
    }
    __syncthreads();
    int o  = t & 63;
    int jg = t >> 6;
    const float* xsj = xs + jg * 8 * H_DIM;
    float acc[8][2] = {};
    for (int k = 0; k < H_DIM; ++k) {
        float w0 = W2[k * O_DIM + o];
        float w1 = W2[k * O_DIM + o + 64];
        #pragma unroll
        for (int j = 0; j < 8; ++j) {
            float x = xsj[j * H_DIM + k];
            acc[j][0] += x * w0; acc[j][1] += x * w1;
        }
    }
    #pragma unroll
    for (int j = 0; j < 8; ++j) {
        size_t base = (size_t)(nb + jg * 8 + j) * O_DIM + o;
        xw2h[base]      = __float2half(acc[j][0]);
        xw2h[base + 64] = __float2half(acc[j][1]);
    }
}

// ---------------- layer-2 agg + relu + LDS-reduced pool (4 nodes/block) ------

__global__ void k_agg2_pool(const __half2* __restrict__ xw2h, const float* __restrict__ b2,
                            const float* __restrict__ dis, const int* __restrict__ offs,
                            const int2* __restrict__ csr, const int* __restrict__ batch,
                            float* __restrict__ pool) {
    __shared__ float2 red[4][64];
    __shared__ int bgs[4];
    int wave = threadIdx.x >> 6;
    int lane = threadIdx.x & 63;
    int c = blockIdx.x * 4 + wave;
    float d = dis[c];
    float2 self = __half22float2(xw2h[(size_t)c * 64 + lane]);
    float2 bb = ((const float2*)b2)[lane];
    float2 esum = {0.f, 0.f};
    int s0 = offs[c], s1 = offs[c + 1];
    int s = s0;
    for (; s + 8 <= s1; s += 8) {
        int sb_i = __builtin_amdgcn_readfirstlane(s);
        int2 e[8];
        #pragma unroll
        for (int u = 0; u < 8; ++u) e[u] = csr[sb_i + u];
        float2 v[8];
        #pragma unroll
        for (int u = 0; u < 8; ++u)
            v[u] = __half22float2(xw2h[(size_t)(e[u].x >> 10) * 64 + lane]);
        #pragma unroll
        for (int u = 0; u < 8; ++u) {
            float n = __int_as_float(e[u].y);
            esum.x += v[u].x * n; esum.y += v[u].y * n;
        }
    }
    for (; s < s1; ++s) {
        int sb_i = __builtin_amdgcn_readfirstlane(s);
        int2 e0 = csr[sb_i];
        float2 v0 = __half22float2(xw2h[(size_t)(e0.x >> 10) * 64 + lane]);
        float n0 = __int_as_float(e0.y);
        esum.x += v0.x * n0; esum.y += v0.y * n0;
    }
    float dd = d * d;
    float2 acc;
    acc.x = bb.x + self.x * dd + d * esum.x;
    acc.y = bb.y + self.y * dd + d * esum.y;
    acc.x = acc.x > 0.0f ? acc.x : 0.0f;
    acc.y = acc.y > 0.0f ? acc.y : 0.0f;
    red[wave][lane] = acc;
    if (lane == 0) bgs[wave] = batch[c];
    __syncthreads();
    if (wave == 0) {
        float2 a = red[0][lane];
        int cg = bgs[0];
        #pragma unroll
        for (int w = 1; w < 4; ++w) {
            int g = bgs[w];
            float2 r = red[w][lane];
            if (g == cg) { a.x += r.x; a.y += r.y; }
            else {
                atomicAdd(&pool[cg * O_DIM + 2 * lane], a.x);
                atomicAdd(&pool[cg * O_DIM + 2 * lane + 1], a.y);
                a = r; cg = g;
            }
        }
        atomicAdd(&pool[cg * O_DIM + 2 * lane], a.x);
        atomicAdd(&pool[cg * O_DIM + 2 * lane + 1], a.y);
    }
}

__global__ void k_final(const float* __restrict__ pool, const float* __restrict__ cnt,
                        float* __restrict__ out) {
    int t = blockIdx.x * blockDim.x + threadIdx.x;
    if (t < N_GRAPH * O_DIM) {
        int g = t / O_DIM;
        out[t] = pool[t] / fmaxf(cnt[g], 1.0f);
    }
}

// ---------------- launch ----------------

extern "C" void kernel_launch(void* const* d_in, const int* in_sizes, int n_in,
                              void* d_out, int out_size, void* d_ws, size_t ws_size,
                              hipStream_t stream) {
    const float* cf   = (const float*)d_in[0];   // [V,128]
    const float* W1   = (const float*)d_in[1];   // [128,256]
    const float* b1   = (const float*)d_in[2];   // [256]
    const float* W2   = (const float*)d_in[3];   // [256,128]
    const float* b2   = (const float*)d_in[4];   // [128]
    const float* ew   = (const float*)d_in[5];   // [E]
    const int*   nidx = (const int*)d_in[6];     // [N]
    const int*   eidx = (const int*)d_in[7];     // [2,E]
    const int*   bidx = (const int*)d_in[8];     // [N]
    float* out = (float*)d_out;

    const int* row = eidx;            // source
    const int* col = eidx + N_EDGES;  // target

    // workspace layout (bytes)
    char* ws = (char*)d_ws;
    size_t off = 0;
    int*   hist  = (int*)  (ws + off); off += (size_t)N_NODES * 4;          // 256K
    int*   hoffs = (int*)  (ws + off); off += (size_t)N_NODES * 4;          // 256K
    int*   bsum  = (int*)  (ws + off); off += 4096;
    float* dis   = (float*)(ws + off); off += (size_t)N_NODES * 4;          // 256K
    int*   offs  = (int*)  (ws + off); off += (size_t)(N_NODES + 16) * 4;   // 256K
    int2*  csr   = (int2*) (ws + off); off += (size_t)N_EDGES * 8;          // 16M
    float* pool  = (float*)(ws + off); off += (size_t)(N_GRAPH * O_DIM + N_GRAPH) * 4;
    __half* cfW1 = (__half*)(ws + off); off += (size_t)V_SIZE * H_DIM * 2;  // 512K
    off = (off + 255) & ~(size_t)255;
    int2*  part  = (int2*) (ws + off); off += (size_t)N_EDGES * 8;          // 16M
    __half* h1   = (__half*)(ws + off);                                     // 32M
    __half* xw2h = (__half*)part;    // part dead after k_build2
    float* cntf  = pool + N_GRAPH * O_DIM;

    // 1. init (pool zero + graph counts + cfW1 table) + histogram + scan
    k_init<<<N_GRAPH * O_DIM / 256, 256, 0, stream>>>(pool, bidx, cntf, cf, W1, cfW1);
    k_hist<<<NBLK, 256, 0, stream>>>(col, hist);
    k_scan1<<<256, 256, 0, stream>>>(hist, hoffs, bsum);
    k_scan2<<<1, 256, 0, stream>>>(bsum);

    // 2. partition -> build1 (deg/dis/offs) -> build2 (CSR w/ nrm applied)
    k_part<<<NBLK, 256, 0, stream>>>(row, col, ew, nidx, hoffs, bsum, part);
    k_build1<<<256, 256, 0, stream>>>(hoffs, bsum, part, dis, offs);
    k_build2<<<256, 256, 0, stream>>>(hoffs, bsum, part, dis, offs, csr);

    // 3. layer 1: gather-aggregate from the 512 KB cfW1 table -> h1 (fp16)
    k_agg1<<<N_NODES / 4, 256, 0, stream>>>((const int2*)cfW1, nidx, dis, offs, csr,
                                            (const float4*)b1, (int2*)h1);

    // 4. layer 2: GEMM (fp16 in/out), aggregate + relu + LDS-reduced pool
    k_gemm2<<<N_NODES / 32, 256, 0, stream>>>(h1, W2, xw2h);
    k_agg2_pool<<<N_NODES / 4, 256, 0, stream>>>((const __half2*)xw2h, b2, dis, offs, csr,
                                                 bidx, pool);

    // 5. final divide
    k_final<<<(N_GRAPH * O_DIM + 255) / 256, 256, 0, stream>>>(pool, cntf, out);
}

// Round 16
// 345.813 us; speedup vs baseline: 1.2536x; 1.0606x over previous
//
#include <hip/hip_runtime.h>
#include <hip/hip_fp16.h>
#include <math.h>

// Problem constants (match reference)
constexpr int N_NODES = 65536;
constexpr int N_EDGES = 2097152;
constexpr int F_IN    = 128;
constexpr int H_DIM   = 256;
constexpr int O_DIM   = 128;
constexpr int N_GRAPH = 256;
constexpr int V_SIZE  = 1000;

// 256 buckets of 256 nodes (bucket = col>>8); 256 edge-blocks of 8192 edges.
constexpr int EPB  = 8192;
constexpr int NBLK = N_EDGES / EPB;   // 256
constexpr float FXP = 16777216.0f;    // 2^24

typedef _Float16 half8 __attribute__((ext_vector_type(8)));
typedef float floatx4 __attribute__((ext_vector_type(4)));

// ---------------- init: pool=0, graph counts, cfW1 table, W2T fp16 ----------
// blocks 0..124: cfW1 = cf@W1 fp16 [1000x256]; block 0 also graph counts;
// blocks 128..255: W2T[n][k] = W2[k][n] fp16 [128x256]; blocks 0..127: pool=0.

__global__ void k_init(float* __restrict__ pool, const int* __restrict__ batch,
                       float* __restrict__ cntf, const float* __restrict__ cf,
                       const float* __restrict__ W1, __half* __restrict__ cfW1,
                       const float* __restrict__ W2, _Float16* __restrict__ W2T) {
    __shared__ float xs[8 * F_IN];    // 4 KB
    int i = blockIdx.x * blockDim.x + threadIdx.x;
    if (i < N_GRAPH * O_DIM) pool[i] = 0.0f;
    if (blockIdx.x == 0) {
        // batch_index sorted: per-graph counts via binary search, no atomics
        int g = threadIdx.x;
        int lo = 0, hi = N_NODES;
        while (lo < hi) { int m = (lo + hi) >> 1; if (batch[m] < g) lo = m + 1; else hi = m; }
        int start = lo;
        lo = 0; hi = N_NODES;
        while (lo < hi) { int m = (lo + hi) >> 1; if (batch[m] <= g) lo = m + 1; else hi = m; }
        cntf[g] = (float)(lo - start);
    }
    if (blockIdx.x < V_SIZE / 8) {    // 125 blocks compute the cfW1 table
        int rb = blockIdx.x * 8;
        int t  = threadIdx.x;
        #pragma unroll
        for (int p = 0; p < 4; ++p) {
            int idx = p * 256 + t;
            int r = idx >> 7, k = idx & 127;
            xs[idx] = cf[(size_t)(rb + r) * F_IN + k];
        }
        __syncthreads();
        float acc[8] = {};
        for (int k = 0; k < F_IN; ++k) {
            float w = W1[k * H_DIM + t];
            #pragma unroll
            for (int j = 0; j < 8; ++j) acc[j] += xs[j * F_IN + k] * w;
        }
        #pragma unroll
        for (int j = 0; j < 8; ++j)
            cfW1[(size_t)(rb + j) * H_DIM + t] = __float2half(acc[j]);
    }
    if (blockIdx.x >= 128) {          // 128 blocks: W2T transpose fp32->fp16
        int idx = (blockIdx.x - 128) * 256 + threadIdx.x;   // 0..32767
        int nn = idx >> 8, kk = idx & 255;
        W2T[idx] = (_Float16)W2[kk * O_DIM + nn];
    }
}

// ---------------- stage A: per-block bucket histogram (LDS) ----------------

__global__ void k_hist(const int* __restrict__ col, int* __restrict__ hist) {
    __shared__ int h[256];
    int t = threadIdx.x;
    h[t] = 0;
    __syncthreads();
    int base = blockIdx.x * EPB;
    #pragma unroll
    for (int i = 0; i < EPB / 256; ++i)
        atomicAdd(&h[col[base + i * 256 + t] >> 8], 1);
    __syncthreads();
    hist[t * NBLK + blockIdx.x] = h[t];   // bucket-major for the scan
}

// ---------------- scan (partial per-256-chunk + block sums) ----------------

__global__ void k_scan1(const int* __restrict__ in, int* __restrict__ out,
                        int* __restrict__ bsum) {
    __shared__ int s[256];
    int tid = threadIdx.x;
    int i = blockIdx.x * 256 + tid;
    int v = in[i];
    s[tid] = v;
    __syncthreads();
    for (int d = 1; d < 256; d <<= 1) {
        int t = (tid >= d) ? s[tid - d] : 0;
        __syncthreads();
        s[tid] += t;
        __syncthreads();
    }
    out[i] = s[tid] - v;
    if (tid == 255) bsum[blockIdx.x] = s[255];
}

__global__ void k_scan2(int* __restrict__ bsum) {
    __shared__ int s[256];
    int tid = threadIdx.x;
    int v = bsum[tid];
    s[tid] = v;
    __syncthreads();
    for (int d = 1; d < 256; d <<= 1) {
        int t = (tid >= d) ? s[tid - d] : 0;
        __syncthreads();
        s[tid] += t;
        __syncthreads();
    }
    bsum[tid] = s[tid] - v;
}

// ---------------- stage C: partition into int2 records ----------------------
// rec.x = src:16 | dst8:8 | vocab_hi:8 ; rec.y = vocab_lo:2<<16 | ew_fp16:16

__global__ void k_part(const int* __restrict__ row, const int* __restrict__ col,
                       const float* __restrict__ ew, const int* __restrict__ nidx,
                       const int* __restrict__ hoffs, const int* __restrict__ bsum,
                       int2* __restrict__ part) {
    __shared__ int cur[256];
    int t = threadIdx.x;
    cur[t] = hoffs[t * NBLK + blockIdx.x] + bsum[t];
    __syncthreads();
    int base = blockIdx.x * EPB;
    for (int i = 0; i < EPB / 256; ++i) {
        int e = base + i * 256 + t;
        int r = row[e], c = col[e];
        unsigned hw = (unsigned)__half_as_ushort(__float2half(ew[e]));
        int vb = nidx[r];
        int slot = atomicAdd(&cur[c >> 8], 1);
        int2 rec;
        rec.x = (r << 16) | ((c & 255) << 8) | (vb >> 2);
        rec.y = (int)(((unsigned)(vb & 3) << 16) | hw);
        part[slot] = rec;
    }
}

// ---------------- stage D1: per-bucket deg/dis + offs (pass 1) --------------

__global__ void k_build1(const int* __restrict__ hoffs, const int* __restrict__ bsum,
                         const int2* __restrict__ part, float* __restrict__ dis,
                         int* __restrict__ offs) {
    __shared__ unsigned long long dc[256];
    __shared__ int sc[256];
    int t = threadIdx.x;
    int bucket = blockIdx.x;
    dc[t] = 0ULL;
    __syncthreads();
    int start = hoffs[bucket * NBLK] + bsum[bucket];
    int end   = (bucket == 255) ? N_EDGES : (hoffs[(bucket + 1) * NBLK] + bsum[bucket + 1]);
    for (int j = start + t; j < end; j += 256) {
        int2 rec = part[j];
        int dst = (rec.x >> 8) & 255;
        float w = __half2float(__ushort_as_half((unsigned short)(rec.y & 0xFFFF)));
        atomicAdd(&dc[dst], (1ULL << 40) |
                  (unsigned long long)(unsigned)(w * FXP + 0.5f));
    }
    __syncthreads();
    unsigned long long v = dc[t];
    float deg = 1.0f + (float)(v & 0xFFFFFFFFFFULL) * (1.0f / FXP);   // self-loop +1
    dis[bucket * 256 + t] = 1.0f / sqrtf(deg);                        // deg >= 1
    int cnt = (int)(v >> 40);
    sc[t] = cnt;
    __syncthreads();
    for (int d = 1; d < 256; d <<= 1) {
        int x = (t >= d) ? sc[t - d] : 0;
        __syncthreads();
        sc[t] += x;
        __syncthreads();
    }
    offs[bucket * 256 + t] = start + sc[t] - cnt;
    if (bucket == 255 && t == 255) offs[N_NODES] = N_EDGES;
}

// ---------------- stage D2: scatter to final CSR with nrm applied -----------
// csr.x = src<<10 | vocab ; csr.y = dis[src] * ew (dis[dst] applied in agg).

__global__ void k_build2(const int* __restrict__ hoffs, const int* __restrict__ bsum,
                         const int2* __restrict__ part, const float* __restrict__ dis,
                         const int* __restrict__ offs, int2* __restrict__ csr) {
    __shared__ int cur[256];
    int t = threadIdx.x;
    int bucket = blockIdx.x;
    cur[t] = offs[bucket * 256 + t];
    __syncthreads();
    int start = hoffs[bucket * NBLK] + bsum[bucket];
    int end   = (bucket == 255) ? N_EDGES : (hoffs[(bucket + 1) * NBLK] + bsum[bucket + 1]);
    for (int j = start + t; j < end; j += 256) {
        int2 rec = part[j];
        int dst = (rec.x >> 8) & 255;
        unsigned src = ((unsigned)rec.x) >> 16;
        int vb = ((rec.x & 255) << 2) | ((rec.y >> 16) & 3);
        float w = __half2float(__ushort_as_half((unsigned short)(rec.y & 0xFFFF)));
        float nm = dis[src] * w;
        int slot = atomicAdd(&cur[dst], 1);
        int2 e;
        e.x = (int)((src << 10) | (unsigned)vb);
        e.y = __float_as_int(nm);
        csr[slot] = e;
    }
}

// ---------------- layer-1: gather-aggregate cfW1 rows -> h1 (fp16) ----------
// wave per node; lane = 4 halves (int2); csr loads on the scalar path.

__global__ void k_agg1(const int2* __restrict__ cfW1, const int* __restrict__ nidx,
                       const float* __restrict__ dis, const int* __restrict__ offs,
                       const int2* __restrict__ csr, const float4* __restrict__ b1f4,
                       int2* __restrict__ h1) {
    int wave = threadIdx.x >> 6;
    int lane = threadIdx.x & 63;
    int c = blockIdx.x * 4 + wave;
    float d = dis[c];
    int2 sp = cfW1[(size_t)nidx[c] * 64 + lane];
    float2 sa = __half22float2(*(__half2*)&sp.x);
    float2 sb = __half22float2(*(__half2*)&sp.y);
    float4 esum = {0.f, 0.f, 0.f, 0.f};
    int a0 = offs[c], a1 = offs[c + 1];
    int s = a0;
    for (; s + 8 <= a1; s += 8) {
        int sb_i = __builtin_amdgcn_readfirstlane(s);
        int2 e[8];
        #pragma unroll
        for (int u = 0; u < 8; ++u) e[u] = csr[sb_i + u];
        int2 v[8];
        #pragma unroll
        for (int u = 0; u < 8; ++u)
            v[u] = cfW1[(size_t)(e[u].x & 1023) * 64 + lane];
        #pragma unroll
        for (int u = 0; u < 8; ++u) {
            float n = __int_as_float(e[u].y);
            float2 va = __half22float2(*(__half2*)&v[u].x);
            float2 vb = __half22float2(*(__half2*)&v[u].y);
            esum.x += va.x * n; esum.y += va.y * n;
            esum.z += vb.x * n; esum.w += vb.y * n;
        }
    }
    for (; s < a1; ++s) {
        int sb_i = __builtin_amdgcn_readfirstlane(s);
        int2 e0 = csr[sb_i];
        int2 v0 = cfW1[(size_t)(e0.x & 1023) * 64 + lane];
        float n = __int_as_float(e0.y);
        float2 va = __half22float2(*(__half2*)&v0.x);
        float2 vb = __half22float2(*(__half2*)&v0.y);
        esum.x += va.x * n; esum.y += va.y * n;
        esum.z += vb.x * n; esum.w += vb.y * n;
    }
    float4 bb = b1f4[lane];
    float dd = d * d;
    float r0 = bb.x + sa.x * dd + d * esum.x;
    float r1 = bb.y + sa.y * dd + d * esum.y;
    float r2 = bb.z + sb.x * dd + d * esum.z;
    float r3 = bb.w + sb.y * dd + d * esum.w;
    r0 = r0 > 0.f ? r0 : 0.f;  r1 = r1 > 0.f ? r1 : 0.f;
    r2 = r2 > 0.f ? r2 : 0.f;  r3 = r3 > 0.f ? r3 : 0.f;
    float2 p0 = {r0, r1}, p1 = {r2, r3};
    __half2 ha = __float22half2_rn(p0);
    __half2 hb = __float22half2_rn(p1);
    int2 outv;
    outv.x = *(int*)&ha;
    outv.y = *(int*)&hb;
    h1[(size_t)c * 64 + lane] = outv;
}

// ---------------- GEMM2 via MFMA: h1 [N,256] fp16 @ W2 -> xw2h fp16 ---------
// Wave per 16-row tile. A: m=lane&15, k=quad*8+j (16 B loads from h1).
// B: n=lane&15, k=quad*8+j (16 B loads from L2-hot W2T[128][256]).
// C/D: col=lane&15, row=quad*4+reg (verified dtype-independent mapping).

__global__ void k_gemm2(const _Float16* __restrict__ h1, const _Float16* __restrict__ W2T,
                        __half* __restrict__ xw2h) {
    int wave = threadIdx.x >> 6;
    int lane = threadIdx.x & 63;
    int quad = lane >> 4;
    int n    = lane & 15;
    int tm   = blockIdx.x * 4 + wave;                  // 16-row tile index
    const _Float16* arow = h1 + (size_t)(tm * 16 + n) * H_DIM;
    half8 a[8];
    #pragma unroll
    for (int kt = 0; kt < 8; ++kt)
        a[kt] = *(const half8*)(arow + kt * 32 + quad * 8);
    #pragma unroll
    for (int nt = 0; nt < 8; ++nt) {
        floatx4 acc = {0.f, 0.f, 0.f, 0.f};
        const _Float16* brow = W2T + (size_t)(nt * 16 + n) * H_DIM;
        #pragma unroll
        for (int kt = 0; kt < 8; ++kt) {
            half8 b = *(const half8*)(brow + kt * 32 + quad * 8);
            acc = __builtin_amdgcn_mfma_f32_16x16x32_f16(a[kt], b, acc, 0, 0, 0);
        }
        #pragma unroll
        for (int r = 0; r < 4; ++r) {
            int rowi = tm * 16 + quad * 4 + r;
            xw2h[(size_t)rowi * O_DIM + nt * 16 + n] = __float2half(acc[r]);
        }
    }
}

// ---------------- layer-2 agg + relu + LDS-reduced pool (4 nodes/block) ------

__global__ void k_agg2_pool(const __half2* __restrict__ xw2h, const float* __restrict__ b2,
                            const float* __restrict__ dis, const int* __restrict__ offs,
                            const int2* __restrict__ csr, const int* __restrict__ batch,
                            float* __restrict__ pool) {
    __shared__ float2 red[4][64];
    __shared__ int bgs[4];
    int wave = threadIdx.x >> 6;
    int lane = threadIdx.x & 63;
    int c = blockIdx.x * 4 + wave;
    float d = dis[c];
    float2 self = __half22float2(xw2h[(size_t)c * 64 + lane]);
    float2 bb = ((const float2*)b2)[lane];
    float2 esum = {0.f, 0.f};
    int s0 = offs[c], s1 = offs[c + 1];
    int s = s0;
    for (; s + 8 <= s1; s += 8) {
        int sb_i = __builtin_amdgcn_readfirstlane(s);
        int2 e[8];
        #pragma unroll
        for (int u = 0; u < 8; ++u) e[u] = csr[sb_i + u];
        float2 v[8];
        #pragma unroll
        for (int u = 0; u < 8; ++u)
            v[u] = __half22float2(xw2h[(size_t)(e[u].x >> 10) * 64 + lane]);
        #pragma unroll
        for (int u = 0; u < 8; ++u) {
            float n = __int_as_float(e[u].y);
            esum.x += v[u].x * n; esum.y += v[u].y * n;
        }
    }
    for (; s < s1; ++s) {
        int sb_i = __builtin_amdgcn_readfirstlane(s);
        int2 e0 = csr[sb_i];
        float2 v0 = __half22float2(xw2h[(size_t)(e0.x >> 10) * 64 + lane]);
        float n0 = __int_as_float(e0.y);
        esum.x += v0.x * n0; esum.y += v0.y * n0;
    }
    float dd = d * d;
    float2 acc;
    acc.x = bb.x + self.x * dd + d * esum.x;
    acc.y = bb.y + self.y * dd + d * esum.y;
    acc.x = acc.x > 0.0f ? acc.x : 0.0f;
    acc.y = acc.y > 0.0f ? acc.y : 0.0f;
    red[wave][lane] = acc;
    if (lane == 0) bgs[wave] = batch[c];
    __syncthreads();
    if (wave == 0) {
        float2 a = red[0][lane];
        int cg = bgs[0];
        #pragma unroll
        for (int w = 1; w < 4; ++w) {
            int g = bgs[w];
            float2 r = red[w][lane];
            if (g == cg) { a.x += r.x; a.y += r.y; }
            else {
                atomicAdd(&pool[cg * O_DIM + 2 * lane], a.x);
                atomicAdd(&pool[cg * O_DIM + 2 * lane + 1], a.y);
                a = r; cg = g;
            }
        }
        atomicAdd(&pool[cg * O_DIM + 2 * lane], a.x);
        atomicAdd(&pool[cg * O_DIM + 2 * lane + 1], a.y);
    }
}

__global__ void k_final(const float* __restrict__ pool, const float* __restrict__ cnt,
                        float* __restrict__ out) {
    int t = blockIdx.x * blockDim.x + threadIdx.x;
    if (t < N_GRAPH * O_DIM) {
        int g = t / O_DIM;
        out[t] = pool[t] / fmaxf(cnt[g], 1.0f);
    }
}

// ---------------- launch ----------------

extern "C" void kernel_launch(void* const* d_in, const int* in_sizes, int n_in,
                              void* d_out, int out_size, void* d_ws, size_t ws_size,
                              hipStream_t stream) {
    const float* cf   = (const float*)d_in[0];   // [V,128]
    const float* W1   = (const float*)d_in[1];   // [128,256]
    const float* b1   = (const float*)d_in[2];   // [256]
    const float* W2   = (const float*)d_in[3];   // [256,128]
    const float* b2   = (const float*)d_in[4];   // [128]
    const float* ew   = (const float*)d_in[5];   // [E]
    const int*   nidx = (const int*)d_in[6];     // [N]
    const int*   eidx = (const int*)d_in[7];     // [2,E]
    const int*   bidx = (const int*)d_in[8];     // [N]
    float* out = (float*)d_out;

    const int* row = eidx;            // source
    const int* col = eidx + N_EDGES;  // target

    // workspace layout (bytes)
    char* ws = (char*)d_ws;
    size_t off = 0;
    int*   hist  = (int*)  (ws + off); off += (size_t)N_NODES * 4;          // 256K
    int*   hoffs = (int*)  (ws + off); off += (size_t)N_NODES * 4;          // 256K
    int*   bsum  = (int*)  (ws + off); off += 4096;
    float* dis   = (float*)(ws + off); off += (size_t)N_NODES * 4;          // 256K
    int*   offs  = (int*)  (ws + off); off += (size_t)(N_NODES + 16) * 4;   // 256K
    int2*  csr   = (int2*) (ws + off); off += (size_t)N_EDGES * 8;          // 16M
    float* pool  = (float*)(ws + off); off += (size_t)(N_GRAPH * O_DIM + N_GRAPH) * 4;
    __half* cfW1 = (__half*)(ws + off); off += (size_t)V_SIZE * H_DIM * 2;  // 512K
    _Float16* W2T = (_Float16*)(ws + off); off += (size_t)O_DIM * H_DIM * 2; // 64K
    off = (off + 255) & ~(size_t)255;
    int2*  part  = (int2*) (ws + off); off += (size_t)N_EDGES * 8;          // 16M
    __half* h1   = (__half*)(ws + off);                                     // 32M
    __half* xw2h = (__half*)part;    // part dead after k_build2
    float* cntf  = pool + N_GRAPH * O_DIM;

    // 1. init (pool zero + counts + cfW1 + W2T) + histogram + scan
    k_init<<<256, 256, 0, stream>>>(pool, bidx, cntf, cf, W1, cfW1, W2, W2T);
    k_hist<<<NBLK, 256, 0, stream>>>(col, hist);
    k_scan1<<<256, 256, 0, stream>>>(hist, hoffs, bsum);
    k_scan2<<<1, 256, 0, stream>>>(bsum);

    // 2. partition -> build1 (deg/dis/offs) -> build2 (CSR w/ nrm applied)
    k_part<<<NBLK, 256, 0, stream>>>(row, col, ew, nidx, hoffs, bsum, part);
    k_build1<<<256, 256, 0, stream>>>(hoffs, bsum, part, dis, offs);
    k_build2<<<256, 256, 0, stream>>>(hoffs, bsum, part, dis, offs, csr);

    // 3. layer 1: gather-aggregate from the 512 KB cfW1 table -> h1 (fp16)
    k_agg1<<<N_NODES / 4, 256, 0, stream>>>((const int2*)cfW1, nidx, dis, offs, csr,
                                            (const float4*)b1, (int2*)h1);

    // 4. layer 2: MFMA GEMM2, then aggregate + relu + LDS-reduced pool
    k_gemm2<<<N_NODES / 64, 256, 0, stream>>>((const _Float16*)h1, W2T, xw2h);
    k_agg2_pool<<<N_NODES / 4, 256, 0, stream>>>((const __half2*)xw2h, b2, dis, offs, csr,
                                                 bidx, pool);

    // 5. final divide
    k_final<<<(N_GRAPH * O_DIM + 255) / 256, 256, 0, stream>>>(pool, cntf, out);
}